// Round 1
// baseline (404.456 us; speedup 1.0000x reference)
//
#include <hip/hip_runtime.h>
#include <stdint.h>

#define BB 16
#define LC 2048
#define LQ 1024
#define DD 512

typedef _Float16 f16x8 __attribute__((ext_vector_type(8)));
typedef _Float16 f16x4 __attribute__((ext_vector_type(4)));
typedef float f32x4 __attribute__((ext_vector_type(4)));

#define MFMA16 __builtin_amdgcn_mfma_f32_16x16x32_f16

__global__ void zero_k(float* __restrict__ p, int n) {
    int i = blockIdx.x * blockDim.x + threadIdx.x;
    if (i < n) p[i] = 0.0f;
}

// Per 64x64 tile of context: write cm = ctx*wm (i,d)-major fp16,
// ct = ctx^T (d,i)-major fp16 (via LDS transpose), and accumulate cb = ctx.wc
__global__ __launch_bounds__(256) void prep_ctx(
    const float* __restrict__ ctx, const float* __restrict__ w,
    _Float16* __restrict__ cm, _Float16* __restrict__ ct, float* __restrict__ cb)
{
    __shared__ _Float16 sm[64][68];
    const int b = blockIdx.z;
    const int i0 = blockIdx.y * 64;
    const int d0 = blockIdx.x * 64;
    const int t = threadIdx.x;
    const int tx = t & 15, ty = t >> 4;      // tx: 4-col chunk, ty: row group
    const float* wc = w;
    const float* wm = w + 2 * DD;
    const float4 wc4 = *(const float4*)(wc + d0 + tx * 4);
    const float4 wm4 = *(const float4*)(wm + d0 + tx * 4);
    for (int k = 0; k < 4; ++k) {
        const int r = ty + 16 * k;
        const int ig = i0 + r;
        const float4 v = *(const float4*)(ctx + ((size_t)(b * LC + ig)) * DD + d0 + tx * 4);
        f16x4 cmv = { (_Float16)(v.x * wm4.x), (_Float16)(v.y * wm4.y),
                      (_Float16)(v.z * wm4.z), (_Float16)(v.w * wm4.w) };
        *(f16x4*)(cm + ((size_t)(b * LC + ig)) * DD + d0 + tx * 4) = cmv;
        sm[tx * 4 + 0][r] = (_Float16)v.x;
        sm[tx * 4 + 1][r] = (_Float16)v.y;
        sm[tx * 4 + 2][r] = (_Float16)v.z;
        sm[tx * 4 + 3][r] = (_Float16)v.w;
        float p = v.x * wc4.x + v.y * wc4.y + v.z * wc4.z + v.w * wc4.w;
        p += __shfl_xor(p, 1); p += __shfl_xor(p, 2);
        p += __shfl_xor(p, 4); p += __shfl_xor(p, 8);
        if (tx == 0) atomicAdd(&cb[b * LC + ig], p);
    }
    __syncthreads();
    for (int k = 0; k < 4; ++k) {
        const int dd = ty + 16 * k;
        f16x4 o = *(const f16x4*)(&sm[dd][tx * 4]);
        *(f16x4*)(ct + ((size_t)(b * DD + d0 + dd)) * LC + i0 + tx * 4) = o;
    }
}

// Per query row: fp16 copy, qb = q.wq, qmask = (sum(q) != 0)
__global__ __launch_bounds__(128) void prep_q(
    const float* __restrict__ q, const float* __restrict__ w,
    _Float16* __restrict__ qh, float* __restrict__ qb, float* __restrict__ qmask)
{
    const int j = blockIdx.x;
    const int t = threadIdx.x;
    const float* wq = w + DD;
    const float4 v = *(const float4*)(q + (size_t)j * DD + t * 4);
    const float4 wq4 = *(const float4*)(wq + t * 4);
    f16x4 qv = { (_Float16)v.x, (_Float16)v.y, (_Float16)v.z, (_Float16)v.w };
    *(f16x4*)(qh + (size_t)j * DD + t * 4) = qv;
    float dq = v.x * wq4.x + v.y * wq4.y + v.z * wq4.z + v.w * wq4.w;
    float sq = v.x + v.y + v.z + v.w;
    for (int m = 1; m < 64; m <<= 1) { dq += __shfl_xor(dq, m); sq += __shfl_xor(sq, m); }
    __shared__ float sd[2], ss[2];
    if ((t & 63) == 0) { sd[t >> 6] = dq; ss[t >> 6] = sq; }
    __syncthreads();
    if (t == 0) {
        qb[j] = sd[0] + sd[1];
        float s = ss[0] + ss[1];
        qmask[j] = (s != 0.0f) ? 1.0f : 0.0f;
    }
}

// GEMM1: E[b,j,i] = exp( qh[j,:].cm[b,i,:] + cb[b,i] + qb[j] ), fp16 out.
// Also lsum[b,j] += row-partial sums (atomics).
// Block: 128(j) x 128(i), 4 waves of 64x64, K=512 in steps of 32.
__global__ __launch_bounds__(256) void gemm1(
    const _Float16* __restrict__ qh, const _Float16* __restrict__ cm,
    const float* __restrict__ cb, const float* __restrict__ qb,
    _Float16* __restrict__ E, float* __restrict__ lsum)
{
    __shared__ __align__(16) _Float16 smA[128 * 40];
    __shared__ __align__(16) _Float16 smB[128 * 40];
    const int b = blockIdx.z;
    const int m0 = blockIdx.x * 128;   // j
    const int n0 = blockIdx.y * 128;   // i
    const int t = threadIdx.x;
    const int lane = t & 63;
    const int wid = t >> 6;
    const int wvm = wid >> 1, wvn = wid & 1;
    const int li = lane & 15, lg = lane >> 4;
    f32x4 acc[4][4] = {};
    const int sr = t >> 1;             // staging row 0..127
    const int sc = (t & 1) * 16;       // staging col chunk (elems)
    const _Float16* Ap = qh + (size_t)(m0 + sr) * DD + sc;
    const _Float16* Bp = cm + ((size_t)(b * LC + n0 + sr)) * DD + sc;
    _Float16* sAp = smA + sr * 40 + sc;
    _Float16* sBp = smB + sr * 40 + sc;
    for (int ks = 0; ks < DD; ks += 32) {
        uint4 a0 = *(const uint4*)(Ap + ks);
        uint4 a1 = *(const uint4*)(Ap + ks + 8);
        uint4 b0 = *(const uint4*)(Bp + ks);
        uint4 b1 = *(const uint4*)(Bp + ks + 8);
        __syncthreads();
        *(uint4*)(sAp) = a0;
        *(uint4*)(sAp + 8) = a1;
        *(uint4*)(sBp) = b0;
        *(uint4*)(sBp + 8) = b1;
        __syncthreads();
        const int ch = lg * 8;
        f16x8 af[4], bf[4];
        #pragma unroll
        for (int mt = 0; mt < 4; ++mt)
            af[mt] = *(const f16x8*)(smA + (wvm * 64 + mt * 16 + li) * 40 + ch);
        #pragma unroll
        for (int nt = 0; nt < 4; ++nt)
            bf[nt] = *(const f16x8*)(smB + (wvn * 64 + nt * 16 + li) * 40 + ch);
        #pragma unroll
        for (int mt = 0; mt < 4; ++mt)
            #pragma unroll
            for (int nt = 0; nt < 4; ++nt)
                acc[mt][nt] = MFMA16(af[mt], bf[nt], acc[mt][nt], 0, 0, 0);
    }
    __syncthreads();
    float* rs = (float*)smA;
    if (t < 128) rs[t] = 0.0f;
    __syncthreads();
    float cbv[4];
    #pragma unroll
    for (int nt = 0; nt < 4; ++nt) cbv[nt] = cb[b * LC + n0 + wvn * 64 + nt * 16 + li];
    #pragma unroll
    for (int mt = 0; mt < 4; ++mt) {
        #pragma unroll
        for (int r = 0; r < 4; ++r) {
            const int jl = wvm * 64 + mt * 16 + lg * 4 + r;
            const int j = m0 + jl;
            const float qbv = qb[j];
            _Float16* Erow = E + ((size_t)(b * LQ + j)) * LC + n0 + wvn * 64;
            float rsv = 0.0f;
            #pragma unroll
            for (int nt = 0; nt < 4; ++nt) {
                float e = __expf(acc[mt][nt][r] + cbv[nt] + qbv);
                rsv += e;
                Erow[nt * 16 + li] = (_Float16)e;
            }
            rsv += __shfl_xor(rsv, 1); rsv += __shfl_xor(rsv, 2);
            rsv += __shfl_xor(rsv, 4); rsv += __shfl_xor(rsv, 8);
            if (li == 0) atomicAdd(&rs[jl], rsv);
        }
    }
    __syncthreads();
    if (t < 128) atomicAdd(&lsum[b * LQ + m0 + t], rs[t]);
}

// GEMM2: H[b,j,d] = (qmask[j]/lsum[b,j]) * sum_i E[b,j,i] * ct[b,d,i]
__global__ __launch_bounds__(256) void gemm2(
    const _Float16* __restrict__ E, const _Float16* __restrict__ ct,
    const float* __restrict__ lsum, const float* __restrict__ qmask,
    float* __restrict__ H)
{
    __shared__ __align__(16) _Float16 smA[128 * 40];
    __shared__ __align__(16) _Float16 smB[128 * 40];
    const int b = blockIdx.z;
    const int m0 = blockIdx.x * 128;   // j
    const int n0 = blockIdx.y * 128;   // d
    const int t = threadIdx.x;
    const int lane = t & 63;
    const int wid = t >> 6;
    const int wvm = wid >> 1, wvn = wid & 1;
    const int li = lane & 15, lg = lane >> 4;
    f32x4 acc[4][4] = {};
    const int sr = t >> 1;
    const int sc = (t & 1) * 16;
    const _Float16* Ap = E + ((size_t)(b * LQ + m0 + sr)) * LC + sc;
    const _Float16* Bp = ct + ((size_t)(b * DD + n0 + sr)) * LC + sc;
    _Float16* sAp = smA + sr * 40 + sc;
    _Float16* sBp = smB + sr * 40 + sc;
    for (int ks = 0; ks < LC; ks += 32) {
        uint4 a0 = *(const uint4*)(Ap + ks);
        uint4 a1 = *(const uint4*)(Ap + ks + 8);
        uint4 b0 = *(const uint4*)(Bp + ks);
        uint4 b1 = *(const uint4*)(Bp + ks + 8);
        __syncthreads();
        *(uint4*)(sAp) = a0;
        *(uint4*)(sAp + 8) = a1;
        *(uint4*)(sBp) = b0;
        *(uint4*)(sBp + 8) = b1;
        __syncthreads();
        const int ch = lg * 8;
        f16x8 af[4], bf[4];
        #pragma unroll
        for (int mt = 0; mt < 4; ++mt)
            af[mt] = *(const f16x8*)(smA + (wvm * 64 + mt * 16 + li) * 40 + ch);
        #pragma unroll
        for (int nt = 0; nt < 4; ++nt)
            bf[nt] = *(const f16x8*)(smB + (wvn * 64 + nt * 16 + li) * 40 + ch);
        #pragma unroll
        for (int mt = 0; mt < 4; ++mt)
            #pragma unroll
            for (int nt = 0; nt < 4; ++nt)
                acc[mt][nt] = MFMA16(af[mt], bf[nt], acc[mt][nt], 0, 0, 0);
    }
    #pragma unroll
    for (int mt = 0; mt < 4; ++mt) {
        #pragma unroll
        for (int r = 0; r < 4; ++r) {
            const int j = m0 + wvm * 64 + mt * 16 + lg * 4 + r;
            const float s = qmask[j] / lsum[b * LQ + j];
            float* Hrow = H + ((size_t)(b * LQ + j)) * DD + n0 + wvn * 64;
            #pragma unroll
            for (int nt = 0; nt < 4; ++nt)
                Hrow[nt * 16 + li] = acc[mt][nt][r] * s;
        }
    }
}

// colsum[b,i] = sum_j (qmask[j]/lsum[b,j]) * E[b,j,i]  (chunked over j, atomics)
__global__ __launch_bounds__(256) void colsum_k(
    const _Float16* __restrict__ E, const float* __restrict__ lsum,
    const float* __restrict__ qmask, float* __restrict__ cs)
{
    __shared__ float ssm[256];
    const int b = blockIdx.z;
    const int i = blockIdx.x * 256 + threadIdx.x;
    const int j0 = blockIdx.y * 256;
    const int jj = j0 + threadIdx.x;
    ssm[threadIdx.x] = qmask[jj] / lsum[b * LQ + jj];
    __syncthreads();
    const _Float16* Eb = E + ((size_t)(b * LQ + j0)) * LC + i;
    float acc = 0.0f;
    #pragma unroll 4
    for (int j = 0; j < 256; ++j)
        acc += (float)Eb[(size_t)j * LC] * ssm[j];
    atomicAdd(&cs[b * LC + i], acc);
}

// G[b,i,0:512] = ctx; G[b,i,512:1024] = ctx * colsum
__global__ __launch_bounds__(128) void gwrite(
    const float* __restrict__ ctx, const float* __restrict__ cs, float* __restrict__ G)
{
    const int b = blockIdx.y, i = blockIdx.x, t = threadIdx.x;
    const float c = cs[b * LC + i];
    const size_t ro = (size_t)(b * LC + i);
    const float4 v = *(const float4*)(ctx + ro * DD + t * 4);
    float4 u; u.x = v.x * c; u.y = v.y * c; u.z = v.z * c; u.w = v.w * c;
    *(float4*)(G + ro * (2 * DD) + t * 4) = v;
    *(float4*)(G + ro * (2 * DD) + DD + t * 4) = u;
}

extern "C" void kernel_launch(void* const* d_in, const int* in_sizes, int n_in,
                              void* d_out, int out_size, void* d_ws, size_t ws_size,
                              hipStream_t stream)
{
    (void)in_sizes; (void)n_in; (void)out_size; (void)ws_size;
    const float* ctx = (const float*)d_in[0];
    const float* qry = (const float*)d_in[1];
    const float* w   = (const float*)d_in[2];
    float* G = (float*)d_out;
    float* H = G + (size_t)BB * LC * (2 * DD);

    char* ws = (char*)d_ws;
    _Float16* E  = (_Float16*)ws;                            // 64 MB
    _Float16* cm = (_Float16*)(ws + ((size_t)64 << 20));     // 32 MB
    _Float16* ct = (_Float16*)(ws + ((size_t)96 << 20));     // 32 MB
    _Float16* qh = (_Float16*)(ws + ((size_t)128 << 20));    // 1 MB
    float* stats = (float*)(ws + ((size_t)130 << 20));
    float* cb    = stats;              // BB*LC
    float* lsum  = cb + BB * LC;       // BB*LQ
    float* cs    = lsum + BB * LQ;     // BB*LC
    float* qb    = cs + BB * LC;       // LQ
    float* qmask = qb + LQ;            // LQ

    const int nzero = BB * LC + BB * LQ + BB * LC;
    zero_k<<<dim3((nzero + 255) / 256), 256, 0, stream>>>(stats, nzero);
    prep_ctx<<<dim3(DD / 64, LC / 64, BB), 256, 0, stream>>>(ctx, w, cm, ct, cb);
    prep_q<<<dim3(LQ), 128, 0, stream>>>(qry, w, qh, qb, qmask);
    gemm1<<<dim3(LQ / 128, LC / 128, BB), 256, 0, stream>>>(qh, cm, cb, qb, E, lsum);
    gemm2<<<dim3(LQ / 128, DD / 128, BB), 256, 0, stream>>>(E, ct, lsum, qmask, H);
    colsum_k<<<dim3(LC / 256, LQ / 256, BB), 256, 0, stream>>>(E, lsum, qmask, cs);
    gwrite<<<dim3(LC, BB), 128, 0, stream>>>(ctx, cs, G);
}

// Round 2
// 391.482 us; speedup vs baseline: 1.0331x; 1.0331x over previous
//
#include <hip/hip_runtime.h>
#include <stdint.h>

#define BB 16
#define LC 2048
#define LQ 1024
#define DD 512

typedef _Float16 f16x8 __attribute__((ext_vector_type(8)));
typedef _Float16 f16x4 __attribute__((ext_vector_type(4)));
typedef float f32x4 __attribute__((ext_vector_type(4)));

#define MFMA16 __builtin_amdgcn_mfma_f32_16x16x32_f16

// Async global->LDS, 16B per lane. LDS dest = wave-uniform base + lane*16.
__device__ __forceinline__ void async16(_Float16* lds, const _Float16* g) {
    __builtin_amdgcn_global_load_lds(
        (const __attribute__((address_space(1))) void*)g,
        (__attribute__((address_space(3))) void*)lds, 16, 0, 0);
}

__global__ void zero_k(float* __restrict__ p, int n) {
    int i = blockIdx.x * blockDim.x + threadIdx.x;
    if (i < n) p[i] = 0.0f;
}

// Per 64x64 tile of context: write cm = ctx*wm (i,d)-major fp16,
// ct = ctx^T (d,i)-major fp16 (via LDS transpose), and accumulate cb = ctx.wc
__global__ __launch_bounds__(256) void prep_ctx(
    const float* __restrict__ ctx, const float* __restrict__ w,
    _Float16* __restrict__ cm, _Float16* __restrict__ ct, float* __restrict__ cb)
{
    __shared__ _Float16 sm[64][68];
    const int b = blockIdx.z;
    const int i0 = blockIdx.y * 64;
    const int d0 = blockIdx.x * 64;
    const int t = threadIdx.x;
    const int tx = t & 15, ty = t >> 4;
    const float* wc = w;
    const float* wm = w + 2 * DD;
    const float4 wc4 = *(const float4*)(wc + d0 + tx * 4);
    const float4 wm4 = *(const float4*)(wm + d0 + tx * 4);
    for (int k = 0; k < 4; ++k) {
        const int r = ty + 16 * k;
        const int ig = i0 + r;
        const float4 v = *(const float4*)(ctx + ((size_t)(b * LC + ig)) * DD + d0 + tx * 4);
        f16x4 cmv = { (_Float16)(v.x * wm4.x), (_Float16)(v.y * wm4.y),
                      (_Float16)(v.z * wm4.z), (_Float16)(v.w * wm4.w) };
        *(f16x4*)(cm + ((size_t)(b * LC + ig)) * DD + d0 + tx * 4) = cmv;
        sm[tx * 4 + 0][r] = (_Float16)v.x;
        sm[tx * 4 + 1][r] = (_Float16)v.y;
        sm[tx * 4 + 2][r] = (_Float16)v.z;
        sm[tx * 4 + 3][r] = (_Float16)v.w;
        float p = v.x * wc4.x + v.y * wc4.y + v.z * wc4.z + v.w * wc4.w;
        p += __shfl_xor(p, 1); p += __shfl_xor(p, 2);
        p += __shfl_xor(p, 4); p += __shfl_xor(p, 8);
        if (tx == 0) atomicAdd(&cb[b * LC + ig], p);
    }
    __syncthreads();
    for (int k = 0; k < 4; ++k) {
        const int dd = ty + 16 * k;
        f16x4 o = *(const f16x4*)(&sm[dd][tx * 4]);
        *(f16x4*)(ct + ((size_t)(b * DD + d0 + dd)) * LC + i0 + tx * 4) = o;
    }
}

// Per query row: fp16 copy, qb = q.wq, qmask = (sum(q) != 0)
__global__ __launch_bounds__(128) void prep_q(
    const float* __restrict__ q, const float* __restrict__ w,
    _Float16* __restrict__ qh, float* __restrict__ qb, float* __restrict__ qmask)
{
    const int j = blockIdx.x;
    const int t = threadIdx.x;
    const float* wq = w + DD;
    const float4 v = *(const float4*)(q + (size_t)j * DD + t * 4);
    const float4 wq4 = *(const float4*)(wq + t * 4);
    f16x4 qv = { (_Float16)v.x, (_Float16)v.y, (_Float16)v.z, (_Float16)v.w };
    *(f16x4*)(qh + (size_t)j * DD + t * 4) = qv;
    float dq = v.x * wq4.x + v.y * wq4.y + v.z * wq4.z + v.w * wq4.w;
    float sq = v.x + v.y + v.z + v.w;
    for (int m = 1; m < 64; m <<= 1) { dq += __shfl_xor(dq, m); sq += __shfl_xor(sq, m); }
    __shared__ float sd[2], ss[2];
    if ((t & 63) == 0) { sd[t >> 6] = dq; ss[t >> 6] = sq; }
    __syncthreads();
    if (t == 0) {
        qb[j] = sd[0] + sd[1];
        float s = ss[0] + ss[1];
        qmask[j] = (s != 0.0f) ? 1.0f : 0.0f;
    }
}

// GEMM1: E[b,j,i] = exp( qh[j,:].cm[b,i,:] + cb[b,i] + qb[j] ), fp16 out.
// Also lsum[b,j] += row-partial sums (atomics).
// m97-style: 128x128 block, BK=32, unpadded 128x32 LDS tiles,
// global_load_lds width-16 staging (4 insts per wave per iter).
// LDS layout (row-major, 64B rows): staging inst covering rows r0..r0+16:
//   lane L writes LDS[r0 + L/4][ (L%4)*8 .. +8 ] = base + L*16 bytes  -> matches HW.
__global__ __launch_bounds__(256) void gemm1(
    const _Float16* __restrict__ qh, const _Float16* __restrict__ cm,
    const float* __restrict__ cb, const float* __restrict__ qb,
    _Float16* __restrict__ E, float* __restrict__ lsum)
{
    __shared__ __align__(16) _Float16 smA[128 * 32];
    __shared__ __align__(16) _Float16 smB[128 * 32];
    const int b = blockIdx.z;
    const int m0 = blockIdx.x * 128;   // j
    const int n0 = blockIdx.y * 128;   // i
    const int t = threadIdx.x;
    const int lane = t & 63;
    const int wid = t >> 6;
    const int wvm = wid >> 1, wvn = wid & 1;
    const int li = lane & 15, lg = lane >> 4;
    f32x4 acc[4][4] = {};
    // staging roles: wave wid covers rows [wid*32, wid*32+32) of A and B tiles
    const int srow = lane >> 2;          // 0..15
    const int scol = (lane & 3) * 8;     // f16 elems within row
    const _Float16* gA0 = qh + (size_t)(m0 + wid * 32 + srow) * DD + scol;
    const _Float16* gA1 = gA0 + (size_t)16 * DD;
    const _Float16* gB0 = cm + ((size_t)(b * LC + n0 + wid * 32 + srow)) * DD + scol;
    const _Float16* gB1 = gB0 + (size_t)16 * DD;
    _Float16* sA0 = smA + wid * 32 * 32;
    _Float16* sA1 = sA0 + 16 * 32;
    _Float16* sB0 = smB + wid * 32 * 32;
    _Float16* sB1 = sB0 + 16 * 32;
    for (int ks = 0; ks < DD; ks += 32) {
        __syncthreads();                 // previous iter's ds_reads done
        async16(sA0, gA0 + ks);
        async16(sA1, gA1 + ks);
        async16(sB0, gB0 + ks);
        async16(sB1, gB1 + ks);
        __syncthreads();                 // staged data visible (barrier drains vmcnt)
        f16x8 af[4], bf[4];
        #pragma unroll
        for (int mt = 0; mt < 4; ++mt)
            af[mt] = *(const f16x8*)(smA + (wvm * 64 + mt * 16 + li) * 32 + lg * 8);
        #pragma unroll
        for (int nt = 0; nt < 4; ++nt)
            bf[nt] = *(const f16x8*)(smB + (wvn * 64 + nt * 16 + li) * 32 + lg * 8);
        #pragma unroll
        for (int mt = 0; mt < 4; ++mt)
            #pragma unroll
            for (int nt = 0; nt < 4; ++nt)
                acc[mt][nt] = MFMA16(af[mt], bf[nt], acc[mt][nt], 0, 0, 0);
    }
    __syncthreads();
    float* rs = (float*)smA;
    if (t < 128) rs[t] = 0.0f;
    __syncthreads();
    float cbv[4];
    #pragma unroll
    for (int nt = 0; nt < 4; ++nt) cbv[nt] = cb[b * LC + n0 + wvn * 64 + nt * 16 + li];
    #pragma unroll
    for (int mt = 0; mt < 4; ++mt) {
        #pragma unroll
        for (int r = 0; r < 4; ++r) {
            const int jl = wvm * 64 + mt * 16 + lg * 4 + r;
            const int j = m0 + jl;
            const float qbv = qb[j];
            _Float16* Erow = E + ((size_t)(b * LQ + j)) * LC + n0 + wvn * 64;
            float rsv = 0.0f;
            #pragma unroll
            for (int nt = 0; nt < 4; ++nt) {
                float e = __expf(acc[mt][nt][r] + cbv[nt] + qbv);
                rsv += e;
                Erow[nt * 16 + li] = (_Float16)e;
            }
            rsv += __shfl_xor(rsv, 1); rsv += __shfl_xor(rsv, 2);
            rsv += __shfl_xor(rsv, 4); rsv += __shfl_xor(rsv, 8);
            if (li == 0) atomicAdd(&rs[jl], rsv);
        }
    }
    __syncthreads();
    if (t < 128) atomicAdd(&lsum[b * LQ + m0 + t], rs[t]);
}

// GEMM2: H[b,j,d] = (qmask[j]/lsum[b,j]) * sum_i E[b,j,i] * ct[b,d,i]
// Same m97-style staging; K = LC = 2048.
__global__ __launch_bounds__(256) void gemm2(
    const _Float16* __restrict__ E, const _Float16* __restrict__ ct,
    const float* __restrict__ lsum, const float* __restrict__ qmask,
    float* __restrict__ H)
{
    __shared__ __align__(16) _Float16 smA[128 * 32];
    __shared__ __align__(16) _Float16 smB[128 * 32];
    const int b = blockIdx.z;
    const int m0 = blockIdx.x * 128;   // j
    const int n0 = blockIdx.y * 128;   // d
    const int t = threadIdx.x;
    const int lane = t & 63;
    const int wid = t >> 6;
    const int wvm = wid >> 1, wvn = wid & 1;
    const int li = lane & 15, lg = lane >> 4;
    f32x4 acc[4][4] = {};
    const int srow = lane >> 2;
    const int scol = (lane & 3) * 8;
    const _Float16* gA0 = E + ((size_t)(b * LQ + m0 + wid * 32 + srow)) * LC + scol;
    const _Float16* gA1 = gA0 + (size_t)16 * LC;
    const _Float16* gB0 = ct + ((size_t)(b * DD + n0 + wid * 32 + srow)) * LC + scol;
    const _Float16* gB1 = gB0 + (size_t)16 * LC;
    _Float16* sA0 = smA + wid * 32 * 32;
    _Float16* sA1 = sA0 + 16 * 32;
    _Float16* sB0 = smB + wid * 32 * 32;
    _Float16* sB1 = sB0 + 16 * 32;
    for (int ks = 0; ks < LC; ks += 32) {
        __syncthreads();
        async16(sA0, gA0 + ks);
        async16(sA1, gA1 + ks);
        async16(sB0, gB0 + ks);
        async16(sB1, gB1 + ks);
        __syncthreads();
        f16x8 af[4], bf[4];
        #pragma unroll
        for (int mt = 0; mt < 4; ++mt)
            af[mt] = *(const f16x8*)(smA + (wvm * 64 + mt * 16 + li) * 32 + lg * 8);
        #pragma unroll
        for (int nt = 0; nt < 4; ++nt)
            bf[nt] = *(const f16x8*)(smB + (wvn * 64 + nt * 16 + li) * 32 + lg * 8);
        #pragma unroll
        for (int mt = 0; mt < 4; ++mt)
            #pragma unroll
            for (int nt = 0; nt < 4; ++nt)
                acc[mt][nt] = MFMA16(af[mt], bf[nt], acc[mt][nt], 0, 0, 0);
    }
    #pragma unroll
    for (int mt = 0; mt < 4; ++mt) {
        #pragma unroll
        for (int r = 0; r < 4; ++r) {
            const int j = m0 + wvm * 64 + mt * 16 + lg * 4 + r;
            const float s = qmask[j] / lsum[b * LQ + j];
            float* Hrow = H + ((size_t)(b * LQ + j)) * DD + n0 + wvn * 64;
            #pragma unroll
            for (int nt = 0; nt < 4; ++nt)
                Hrow[nt * 16 + li] = acc[mt][nt][r] * s;
        }
    }
}

// colsum[b,i] = sum_j (qmask[j]/lsum[b,j]) * E[b,j,i]
// Vectorized: thread t owns i = t*8..t*8+8 (f16x8 loads), 64-j chunk per block.
__global__ __launch_bounds__(256) void colsum_k(
    const _Float16* __restrict__ E, const float* __restrict__ lsum,
    const float* __restrict__ qmask, float* __restrict__ cs)
{
    __shared__ float ssm[64];
    const int b = blockIdx.y;
    const int j0 = blockIdx.x * 64;
    const int t = threadIdx.x;
    if (t < 64) {
        const int jj = j0 + t;
        ssm[t] = qmask[jj] / lsum[b * LQ + jj];
    }
    __syncthreads();
    const _Float16* Eb = E + ((size_t)(b * LQ + j0)) * LC + t * 8;
    float acc[8] = {};
    #pragma unroll 4
    for (int j = 0; j < 64; ++j) {
        f16x8 v = *(const f16x8*)(Eb + (size_t)j * LC);
        const float s = ssm[j];
        #pragma unroll
        for (int q = 0; q < 8; ++q) acc[q] += s * (float)v[q];
    }
    float* base = cs + b * LC + t * 8;
    #pragma unroll
    for (int q = 0; q < 8; ++q) atomicAdd(base + q, acc[q]);
}

// G[b,i,0:512] = ctx; G[b,i,512:1024] = ctx * colsum
__global__ __launch_bounds__(128) void gwrite(
    const float* __restrict__ ctx, const float* __restrict__ cs, float* __restrict__ G)
{
    const int b = blockIdx.y, i = blockIdx.x, t = threadIdx.x;
    const float c = cs[b * LC + i];
    const size_t ro = (size_t)(b * LC + i);
    const float4 v = *(const float4*)(ctx + ro * DD + t * 4);
    float4 u; u.x = v.x * c; u.y = v.y * c; u.z = v.z * c; u.w = v.w * c;
    *(float4*)(G + ro * (2 * DD) + t * 4) = v;
    *(float4*)(G + ro * (2 * DD) + DD + t * 4) = u;
}

extern "C" void kernel_launch(void* const* d_in, const int* in_sizes, int n_in,
                              void* d_out, int out_size, void* d_ws, size_t ws_size,
                              hipStream_t stream)
{
    (void)in_sizes; (void)n_in; (void)out_size; (void)ws_size;
    const float* ctx = (const float*)d_in[0];
    const float* qry = (const float*)d_in[1];
    const float* w   = (const float*)d_in[2];
    float* G = (float*)d_out;
    float* H = G + (size_t)BB * LC * (2 * DD);

    char* ws = (char*)d_ws;
    _Float16* E  = (_Float16*)ws;                            // 64 MB
    _Float16* cm = (_Float16*)(ws + ((size_t)64 << 20));     // 32 MB
    _Float16* ct = (_Float16*)(ws + ((size_t)96 << 20));     // 32 MB
    _Float16* qh = (_Float16*)(ws + ((size_t)128 << 20));    // 1 MB
    float* stats = (float*)(ws + ((size_t)130 << 20));
    float* cb    = stats;              // BB*LC
    float* lsum  = cb + BB * LC;       // BB*LQ
    float* cs    = lsum + BB * LQ;     // BB*LC
    float* qb    = cs + BB * LC;       // LQ
    float* qmask = qb + LQ;            // LQ

    const int nzero = BB * LC + BB * LQ + BB * LC;
    zero_k<<<dim3((nzero + 255) / 256), 256, 0, stream>>>(stats, nzero);
    prep_ctx<<<dim3(DD / 64, LC / 64, BB), 256, 0, stream>>>(ctx, w, cm, ct, cb);
    prep_q<<<dim3(LQ), 128, 0, stream>>>(qry, w, qh, qb, qmask);
    gemm1<<<dim3(LQ / 128, LC / 128, BB), 256, 0, stream>>>(qh, cm, cb, qb, E, lsum);
    gemm2<<<dim3(LQ / 128, DD / 128, BB), 256, 0, stream>>>(E, ct, lsum, qmask, H);
    colsum_k<<<dim3(LQ / 64, BB), 256, 0, stream>>>(E, lsum, qmask, cs);
    gwrite<<<dim3(LC, BB), 128, 0, stream>>>(ctx, cs, G);
}